// Round 1
// 2435.140 us; speedup vs baseline: 1.2981x; 1.2981x over previous
//
#include <hip/hip_runtime.h>
#include <hip/hip_bf16.h>

#define B_ 64
#define N_ 1000
#define NP 1024
#define D_ 256
#define L_ 7
#define MP (B_*NP)        // 65536 padded rows total
#define PKB 262144        // u16 elements per batch in packed operand buffers

typedef unsigned short u16;
typedef __attribute__((ext_vector_type(4))) float f32x4;
typedef __bf16 bf16x8 __attribute__((ext_vector_type(8)));

static __device__ __forceinline__ u16 f2bf(float f) {
  __hip_bfloat16 h = __float2bfloat16(f);
  return *reinterpret_cast<u16*>(&h);
}
static __device__ __forceinline__ float bf2f(u16 u) {
  __hip_bfloat16 h;
  *reinterpret_cast<u16*>(&h) = u;
  return __bfloat162float(h);
}

// ---------------- pack adjacency into bitmask (diag forced on) ----------------
__global__ __launch_bounds__(64) void pack_mask_k(const float* __restrict__ adj,
                                                  unsigned long long* __restrict__ mask) {
  int row = blockIdx.x;              // b*N_ + i
  int b = row / N_, i = row - b * N_;
  int lane = threadIdx.x;            // 64 threads
  const float* arow = adj + (size_t)(b * N_ + i) * N_;
  #pragma unroll
  for (int j0 = 0; j0 < NP; j0 += 64) {
    int j = j0 + lane;
    bool on = (j < N_) && (arow[j] != 0.0f || j == i);
    unsigned long long m = __ballot(on);
    if (lane == 0) mask[((size_t)(b * NP + i)) * 16 + (j0 >> 6)] = m;
  }
}

// ---------------- convert weights to bf16 in MFMA-fragment-packed layout ----------------
__global__ __launch_bounds__(256) void conv_w_k(const float* __restrict__ Wa,
                                                const float* __restrict__ W0,
                                                const float* __restrict__ W1,
                                                const float* __restrict__ Wf,
                                                u16* __restrict__ wpk) {
  int T = blockIdx.x * 256 + threadIdx.x;   // one 16B frag-slot
  const int NW = 3 * L_ + 1;
  if (T >= NW * 128 * 64) return;
  int lane = T & 63;
  int fid = T >> 6;
  int k = fid & 7, f = (fid >> 3) & 3, by = (fid >> 5) & 3, w = fid >> 7;
  const float* src;
  if (w < L_) src = Wa + (size_t)w * D_ * D_;
  else if (w < 2 * L_) src = W0 + (size_t)(w - L_) * D_ * D_;
  else if (w < 3 * L_) src = W1 + (size_t)(w - 2 * L_) * D_ * D_;
  else src = Wf;
  int row = by * 64 + f * 16 + (lane & 15);
  int col = k * 32 + ((lane >> 4) << 3);
  const float* s = src + (size_t)row * D_ + col;
  u16 out8[8];
  #pragma unroll
  for (int e = 0; e < 8; e++) out8[e] = f2bf(s[e]);
  *reinterpret_cast<bf16x8*>(wpk + (size_t)T * 8) =
      *reinterpret_cast<bf16x8*>(out8);
}

// ---------------- copy input x into padded fp32 + bf16, zero pad rows ----------------
__global__ __launch_bounds__(256) void prep_x_k(const float* __restrict__ x,
                                                float* __restrict__ xc,
                                                u16* __restrict__ xb) {
  size_t t = (size_t)blockIdx.x * blockDim.x + threadIdx.x;
  const size_t total = (size_t)B_ * N_ * D_;
  if (t < total) {
    int b = (int)(t / (N_ * D_));
    int rem = (int)(t - (size_t)b * (N_ * D_));
    size_t o = (size_t)b * NP * D_ + rem;
    float v = x[t];
    xc[o] = v;
    xb[o] = f2bf(v);
  }
  const size_t padTotal = (size_t)B_ * (NP - N_) * D_;
  if (t < padTotal) {
    int b = (int)(t / ((NP - N_) * D_));
    int rem = (int)(t - (size_t)b * ((NP - N_) * D_));
    size_t o = (size_t)b * NP * D_ + (size_t)N_ * D_ + rem;
    xc[o] = 0.f;
    xb[o] = 0;
  }
}

// ---------------- prologue pack: xb -> xpk (QK B / linear A frags) + pvpk (PV B frags) ----
__global__ __launch_bounds__(256) void pack_both_k(const u16* __restrict__ xb,
                                                   u16* __restrict__ xpk,
                                                   u16* __restrict__ pvpk) {
  __shared__ u16 t[64][65];
  int b = blockIdx.z;
  int cc = blockIdx.x;               // j-chunk index (16)
  int bd = blockIdx.y;               // 64-wide d block (4)
  int i0 = cc * 64, d0 = bd * 64;
  int tid = threadIdx.x;
  int tx = tid & 63, ty = tid >> 6;
  const u16* src = xb + (size_t)b * NP * D_;
  #pragma unroll
  for (int r = ty; r < 64; r += 4)
    t[r][tx] = src[(size_t)(i0 + r) * D_ + d0 + tx];   // t[j-local][d-local]
  __syncthreads();
  int lane = tid & 63, q = tid >> 6;
  int l4 = lane >> 4, l15 = lane & 15;
  int dh = bd >> 1, dcb = (bd & 1) * 4;
  u16* dstp = pvpk + (size_t)b * PKB;
  #pragma unroll
  for (int kk = 0; kk < 2; kk++) {
    int frag = cc * 32 + dh * 16 + (dcb + q) * 2 + kk;
    bf16x8 v;
    #pragma unroll
    for (int e = 0; e < 8; e++)
      v[e] = *reinterpret_cast<const __bf16*>(&t[kk * 32 + (l4 << 3) + e][q * 16 + l15]);
    *reinterpret_cast<bf16x8*>(dstp + (size_t)frag * 512 + lane * 8) = v;
  }
  u16* dstq = xpk + (size_t)b * PKB;
  #pragma unroll
  for (int kk = 0; kk < 2; kk++) {
    int frag = cc * 32 + q * 8 + (2 * bd + kk);
    bf16x8 v;
    #pragma unroll
    for (int e = 0; e < 8; e++)
      v[e] = *reinterpret_cast<const __bf16*>(&t[l15 + 16 * q][kk * 32 + (l4 << 3) + e]);
    *reinterpret_cast<bf16x8*>(dstq + (size_t)frag * 512 + lane * 8) = v;
  }
}

// ---------------- generic linear: y = A @ W.T + bias (W fragment-packed) ----------------
// MODE 3: fp32 compact out | 4: A-frag-packed out (q) | 5: relu + row-major bf16 out (h0)
// MODE 6: relu + residual(xc) -> xc fp32 + scatter to xpk (outb) AND pvpk (xbp)
// APK: A operand is fragment-packed (coalesced reads)
template <int MODE, int APK>
__global__ __launch_bounds__(256) void linear_k(const u16* __restrict__ A,
                                                const u16* __restrict__ W,   // packed
                                                const float* __restrict__ bias,
                                                u16* __restrict__ outb,
                                                float* __restrict__ xc,
                                                u16* __restrict__ xbp,
                                                float* __restrict__ outf) {
  int lane = threadIdx.x & 63;
  int wv = threadIdx.x >> 6;
  int rbase = blockIdx.x * 64 + wv * 16;
  int cbase = blockIdx.y * 64;
  f32x4 acc[4] = {};
  const u16* Ar;
  if (APK) Ar = A + ((size_t)(rbase >> 4) << 12) + lane * 8;
  else     Ar = A + (size_t)(rbase + (lane & 15)) * D_ + ((lane >> 4) << 3);
  const u16* Wr = W + (size_t)blockIdx.y * (32 * 512) + lane * 8;   // coalesced frags
  #pragma unroll
  for (int k = 0; k < 8; k++) {
    bf16x8 a = APK ? *reinterpret_cast<const bf16x8*>(Ar + k * 512)
                   : *reinterpret_cast<const bf16x8*>(Ar + k * 32);
    #pragma unroll
    for (int f = 0; f < 4; f++) {
      bf16x8 bb = *reinterpret_cast<const bf16x8*>(Wr + (f * 8 + k) * 512);
      acc[f] = __builtin_amdgcn_mfma_f32_16x16x32_bf16(a, bb, acc[f], 0, 0, 0);
    }
  }
  int r0 = rbase + ((lane >> 4) << 2);
  int col = cbase + (lane & 15);
  #pragma unroll
  for (int f = 0; f < 4; f++) {
    int c = col + f * 16;
    float bv = bias[c];
    #pragma unroll
    for (int r = 0; r < 4; r++) {
      int row = r0 + r;
      float v = acc[f][r] + bv;
      if (MODE == 3) {
        int b = row >> 10, i = row & (NP - 1);
        if (i < N_) outf[((size_t)b * N_ + i) * D_ + c] = v;
      } else if (MODE == 4) {
        size_t dst = ((size_t)(row >> 4) << 12) + ((c >> 5) << 9) +
                     ((((c >> 3) & 3) * 16 + (row & 15)) << 3) + (c & 7);
        outb[dst] = f2bf(v);
      } else if (MODE == 5) {
        v = fmaxf(v, 0.f);
        outb[(size_t)row * D_ + c] = f2bf(v);
      } else {  // MODE 6
        v = fmaxf(v, 0.f);
        size_t o = (size_t)row * D_ + c;
        float nv = v + xc[o];
        xc[o] = nv;
        u16 q16 = f2bf(nv);
        // xpk scatter (A-frag layout, global-row addressed)
        size_t dx = ((size_t)(row >> 4) << 12) + ((c >> 5) << 9) +
                    ((((c >> 3) & 3) * 16 + (row & 15)) << 3) + (c & 7);
        outb[dx] = q16;
        // pvpk scatter (transposed fragment layout, per batch)
        int bb = row >> 10, ri = row & (NP - 1);
        size_t fragp = (size_t)(ri >> 6) * 32 + (c >> 7) * 16 +
                       (((c >> 4) & 7) * 2) + ((ri >> 5) & 1);
        size_t dp = (size_t)bb * PKB + fragp * 512 +
                    ((((ri >> 3) & 3) * 16 + (c & 15)) << 3) + (ri & 7);
        xbp[dp] = q16;
      }
    }
  }
}

// ---------------- fused attention: Y = (mask*(sigmoid(q x^T)+eps*I)) @ x / rowsum ----------
// R12: 64-row blocks, 8 waves (512 thr), grid 1024. 4x arithmetic intensity vs
// the 16-row version (x streamed once per 64 rows, chunk B-frags L1-shared by
// 4 waves). Pair-level software pipeline: per chunk-pair cp the body does
//   QK(cp)  [waves 0-3 chunk 2cp, waves 4-7 chunk 2cp+1]
//   PV(cp-1) [each wave: both chunks, its 32-col d-slice]   (reads plds[parity^1])
//   sigmoid(cp) -> plds[parity]
// with ONE barrier per pair; parity-double-buffered P lets PV loads/MFMAs
// overlap QK and sigmoid in the same scheduling region (no exposed post-barrier
// load cluster). Accumulation order over chunks is identical to R11 (bitwise-
// same MFMA sequence per accumulator); only den summation order differs (fp32,
// << bf16 noise). __launch_bounds__(512,4) caps VGPR at 128 -> 2 blocks/CU.
__global__ __launch_bounds__(512, 4) void attn_fused_k(const u16* __restrict__ qpk,
                                                       const u16* __restrict__ xpk,
                                                       const u16* __restrict__ pvpk,
                                                       const unsigned long long* __restrict__ mask,
                                                       u16* __restrict__ yb) {
  __shared__ u16 plds[2][2][64][72];   // [parity][pair-half][row][j pad 8]
  __shared__ float dlds[8][16];        // [wave][row&15] den partials
  int wg = blockIdx.x;                 // 1024 = 64 b * 16 row-blocks
  int xcd = wg & 7, slot = wg >> 3;    // bijective XCD swizzle (1024 % 8 == 0)
  int b = xcd * 8 + (slot >> 4);       // 8 batches per XCD, 16 blocks/batch adjacent
  int rb = slot & 15;
  int rbase = rb * 64;
  int lane = threadIdx.x & 63;
  int wv = threadIdx.x >> 6;           // 0..7
  int rsub = wv & 3, ph = wv >> 2;     // row-subtile for QK, pair-half
  int l15 = lane & 15, l4 = lane >> 4;
  int rowL = rsub * 16 + l4 * 4;       // local row base owned for sigmoid

  const u16* qpkB = qpk + ((((size_t)b * NP + rbase + rsub * 16) >> 4) << 12) + lane * 8;
  const u16* xpkB = xpk + (size_t)b * PKB + lane * 8;
  // wave's PV d-slice: d = wv*32 + ct*16 + l15  ->  frag = cc*32 + ph*16 + rsub*4 + ct*2 + kk
  const u16* pvkB = pvpk + (size_t)b * PKB + (size_t)(ph * 16 + rsub * 4) * 512 + lane * 8;
  const unsigned long long* mB = mask + (size_t)b * (NP * 16);

  f32x4 yacc[4][2] = {};               // [row-tile][col-tile], 64 rows x 32 cols
  float denp[4] = {0.f, 0.f, 0.f, 0.f};

  #pragma unroll 1
  for (int cp = 0; cp < 8; cp++) {
    int c = cp * 2 + ph;               // my QK chunk this pair
    int pb = cp & 1;
    const u16* xc0 = xpkB + (size_t)c * (32 * 512);
    // ---- QK^T: my 16 rows x 64 j of chunk c (4 waves share chunk via L1) ----
    f32x4 sacc[4] = {};
    __builtin_amdgcn_s_setprio(1);
    #pragma unroll
    for (int k = 0; k < 8; k++) {
      bf16x8 a = *reinterpret_cast<const bf16x8*>(qpkB + k * 512);
      #pragma unroll
      for (int f = 0; f < 4; f++) {
        bf16x8 bb = *reinterpret_cast<const bf16x8*>(xc0 + (f * 8 + k) * 512);
        sacc[f] = __builtin_amdgcn_mfma_f32_16x16x32_bf16(a, bb, sacc[f], 0, 0, 0);
      }
    }
    __builtin_amdgcn_s_setprio(0);
    // ---- PV for previous pair: both chunks, all 64 rows, my 32 d-cols ----
    if (cp > 0) {
      int pr = pb ^ 1;
      __builtin_amdgcn_s_setprio(1);
      #pragma unroll
      for (int pc = 0; pc < 2; pc++) {
        const u16* pvc = pvkB + (size_t)((cp - 1) * 2 + pc) * (32 * 512);
        #pragma unroll
        for (int kk = 0; kk < 2; kk++) {
          bf16x8 b0 = *reinterpret_cast<const bf16x8*>(pvc + kk * 512);
          bf16x8 b1 = *reinterpret_cast<const bf16x8*>(pvc + (2 + kk) * 512);
          #pragma unroll
          for (int rt = 0; rt < 4; rt++) {
            bf16x8 ap = *reinterpret_cast<const bf16x8*>(
                &plds[pr][pc][rt * 16 + l15][kk * 32 + (l4 << 3)]);
            yacc[rt][0] = __builtin_amdgcn_mfma_f32_16x16x32_bf16(ap, b0, yacc[rt][0], 0, 0, 0);
            yacc[rt][1] = __builtin_amdgcn_mfma_f32_16x16x32_bf16(ap, b1, yacc[rt][1], 0, 0, 0);
          }
        }
      }
      __builtin_amdgcn_s_setprio(0);
    }
    // ---- sigmoid + mask + eps-diag -> bf16 P in plds[pb][ph] + den partials ----
    int cb64 = c * 64;
    #pragma unroll
    for (int r = 0; r < 4; r++) {
      int i = rbase + rowL + r;
      unsigned long long mw = (i < N_) ? mB[((size_t)i << 4) + c] : 0ull;
      #pragma unroll
      for (int f = 0; f < 4; f++) {
        int j = cb64 + f * 16 + l15;
        float w = 0.f;
        if ((mw >> (f * 16 + l15)) & 1ull) {
          float s = 1.f / (1.f + __expf(-sacc[f][r]));
          w = s + (i == j ? 1e-5f : 0.f);
        }
        u16 wq = f2bf(w);
        plds[pb][ph][rowL + r][f * 16 + l15] = wq;
        denp[r] += bf2f(wq);
      }
    }
    __syncthreads();   // publish plds[pb]; protects plds[pb^1] overwrite next iter
  }
  // ---- final PV: pair 7 (parity 1) ----
  {
    __builtin_amdgcn_s_setprio(1);
    #pragma unroll
    for (int pc = 0; pc < 2; pc++) {
      const u16* pvc = pvkB + (size_t)(14 + pc) * (32 * 512);
      #pragma unroll
      for (int kk = 0; kk < 2; kk++) {
        bf16x8 b0 = *reinterpret_cast<const bf16x8*>(pvc + kk * 512);
        bf16x8 b1 = *reinterpret_cast<const bf16x8*>(pvc + (2 + kk) * 512);
        #pragma unroll
        for (int rt = 0; rt < 4; rt++) {
          bf16x8 ap = *reinterpret_cast<const bf16x8*>(
              &plds[1][pc][rt * 16 + l15][kk * 32 + (l4 << 3)]);
          yacc[rt][0] = __builtin_amdgcn_mfma_f32_16x16x32_bf16(ap, b0, yacc[rt][0], 0, 0, 0);
          yacc[rt][1] = __builtin_amdgcn_mfma_f32_16x16x32_bf16(ap, b1, yacc[rt][1], 0, 0, 0);
        }
      }
    }
    __builtin_amdgcn_s_setprio(0);
  }
  // ---- den: 16-lane reduce per wave -> cross-wave (ph=0/1) sum via LDS ----
  #pragma unroll
  for (int r = 0; r < 4; r++) {
    float d = denp[r];
    #pragma unroll
    for (int m = 1; m < 16; m <<= 1) d += __shfl_xor(d, m, 64);
    if (l15 == 0) dlds[wv][l4 * 4 + r] = d;
  }
  __syncthreads();
  // ---- epilogue: row-major bf16 out, my 32 d-cols of all 64 rows ----
  u16* yB = yb + ((size_t)b * NP + rbase) * D_ + wv * 32 + l15;
  #pragma unroll
  for (int rt = 0; rt < 4; rt++) {
    #pragma unroll
    for (int r = 0; r < 4; r++) {
      int rl = rt * 16 + l4 * 4 + r;
      int i = rbase + rl;
      float den = dlds[rt][l4 * 4 + r] + dlds[rt + 4][l4 * 4 + r];
      float inv = (i < N_ && den > 0.f) ? 1.f / den : 0.f;
      #pragma unroll
      for (int ct = 0; ct < 2; ct++)
        yB[(size_t)rl * D_ + ct * 16] = f2bf(yacc[rt][ct][r] * inv);
    }
  }
}

extern "C" void kernel_launch(void* const* d_in, const int* in_sizes, int n_in,
                              void* d_out, int out_size, void* d_ws, size_t ws_size,
                              hipStream_t stream) {
  const float* x   = (const float*)d_in[0];
  const float* adj = (const float*)d_in[1];
  const float* Wa  = (const float*)d_in[2];
  const float* ba  = (const float*)d_in[3];
  const float* W0  = (const float*)d_in[4];
  const float* b0_ = (const float*)d_in[5];
  const float* W1  = (const float*)d_in[6];
  const float* b1_ = (const float*)d_in[7];
  const float* Wf  = (const float*)d_in[8];
  const float* bff = (const float*)d_in[9];
  float* out = (float*)d_out;

  char* p = (char*)d_ws;
  auto alloc = [&](size_t bytes) {
    char* r = p;
    p += (bytes + 255) & ~(size_t)255;
    return r;
  };
  unsigned long long* mask = (unsigned long long*)alloc((size_t)B_ * NP * 16 * 8);
  u16* xb    = (u16*)alloc((size_t)MP * D_ * 2);   // prologue only
  u16* xpk   = (u16*)alloc((size_t)B_ * PKB * 2);  // x: QK-B frags == linear-A frags
  u16* pvpk  = (u16*)alloc((size_t)B_ * PKB * 2);  // x^T: PV-B frags
  u16* qpk   = (u16*)alloc((size_t)MP * D_ * 2);   // q, A-frag-packed
  u16* slotA = (u16*)alloc((size_t)MP * D_ * 2);   // h0, row-major
  u16* slotB = (u16*)alloc((size_t)MP * D_ * 2);   // attn out, row-major
  float* xc  = (float*)alloc((size_t)MP * D_ * 4);
  u16* wb    = (u16*)alloc((size_t)(3 * L_ + 1) * D_ * D_ * 2);

  pack_mask_k<<<dim3(B_ * N_), dim3(64), 0, stream>>>(adj, mask);
  conv_w_k<<<dim3(704), dim3(256), 0, stream>>>(Wa, W0, W1, Wf, wb);
  prep_x_k<<<dim3((B_ * N_ * D_ + 255) / 256), dim3(256), 0, stream>>>(x, xc, xb);
  pack_both_k<<<dim3(16, 4, B_), dim3(256), 0, stream>>>(xb, xpk, pvpk);

  for (int l = 0; l < L_; l++) {
    const u16* wAttn = wb + (size_t)l * D_ * D_;
    const u16* w0l = wb + (size_t)(L_ + l) * D_ * D_;
    const u16* w1l = wb + (size_t)(2 * L_ + l) * D_ * D_;

    linear_k<4, 1><<<dim3(MP / 64, D_ / 64), dim3(256), 0, stream>>>(
        xpk, wAttn, ba + l * D_, qpk, nullptr, nullptr, nullptr);
    attn_fused_k<<<dim3(1024), dim3(512), 0, stream>>>(
        qpk, xpk, pvpk, mask, slotB);
    linear_k<5, 0><<<dim3(MP / 64, D_ / 64), dim3(256), 0, stream>>>(
        slotB, w0l, b0_ + l * D_, slotA, nullptr, nullptr, nullptr);
    linear_k<6, 0><<<dim3(MP / 64, D_ / 64), dim3(256), 0, stream>>>(
        slotA, w1l, b1_ + l * D_, xpk, xc, pvpk, nullptr);
  }
  linear_k<3, 1><<<dim3(MP / 64, D_ / 64), dim3(256), 0, stream>>>(
      xpk, wb + (size_t)3 * L_ * D_ * D_, bff, nullptr, nullptr, nullptr, out);
}